// Round 4
// baseline (161.064 us; speedup 1.0000x reference)
//
#include <hip/hip_runtime.h>

#define TX 64        // output tile width
#define TY 16        // output tile height
#define HY 26        // halo height (TY + 10)
#define SHP 68       // sH row stride in elements (64 + 4 pad -> conflict-free)
#define NT 256
#define IMG 512

typedef _Float16 h2 __attribute__((ext_vector_type(2)));

__device__ inline unsigned int pack_rtz_u(float a, float b) {
    auto r = __builtin_amdgcn_cvt_pkrtz(a, b);   // __fp16 ext_vector(2)
    return __builtin_bit_cast(unsigned int, r);
}

// ---------------------------------------------------------------------------
// Fused SSIM tile kernel.
// Phase 1: 208 threads (26 rows x 8 col-groups) read 24 raw px/image from
//          global (aligned float4, zero OOB), horizontal-convolve 8 outputs x
//          5 moment channels, pack (P,T),(PP,TT) to f16x2 + PT f32, write LDS.
// Phase 2: 256 threads (64 cols x 4 row-groups of 4) vertical-convolve with
//          v_pk_fma_f16 (+ f32 for PT), SSIM, block reduce.
// ---------------------------------------------------------------------------
__global__ __launch_bounds__(NT, 7) void ssim_tile_kernel(
    const float* __restrict__ pred,
    const float* __restrict__ target,
    const float* __restrict__ kern,
    float* __restrict__ partial)
{
    __shared__ __align__(16) unsigned int sPk1[HY][SHP];  // f16x2 (P, T)
    __shared__ __align__(16) unsigned int sPk2[HY][SHP];  // f16x2 (PP, TT)
    __shared__ __align__(16) float        sPT [HY][SHP];  // f32 PT
    __shared__ float sRed[4];

    const int tid = threadIdx.x;
    const int tx0 = blockIdx.x * TX;
    const int ty0 = blockIdx.y * TY;
    const int img = blockIdx.z;

    // 1D gaussian weights from center row of the 2D kernel: k2d[5][j] = g5*gj
    float w[11];
    h2    wh[11];
    {
        const float inv_g5 = 1.0f / sqrtf(kern[60]);
        #pragma unroll
        for (int j = 0; j < 11; ++j) {
            w[j] = kern[55 + j] * inv_g5;
            const _Float16 wf = (_Float16)w[j];
            wh[j] = h2{wf, wf};
        }
    }

    // ---- phase 1: global -> registers -> horizontal conv -> packed LDS ----
    if (tid < 208) {
        const int r  = tid >> 3;        // 0..25  (halo row)
        const int xg = tid & 7;         // 0..7   (8-output column group)
        const int gy = ty0 + r - 5;
        const int cb = tx0 + (xg << 3) - 8;   // aligned float4 base
        const bool rowok = (unsigned)gy < IMG;

        const float* prow = pred   + (size_t)img * (IMG * IMG) + gy * IMG;
        const float* trow = target + (size_t)img * (IMG * IMG) + gy * IMG;

        float p[24], t[24];
        #pragma unroll
        for (int q = 0; q < 6; ++q) {
            const int c0 = cb + (q << 2);
            float4 pv = make_float4(0.f, 0.f, 0.f, 0.f);
            float4 tv = make_float4(0.f, 0.f, 0.f, 0.f);
            if (rowok && (unsigned)c0 < IMG) {   // c0 % 4 == 0
                pv = *(const float4*)(prow + c0);
                tv = *(const float4*)(trow + c0);
            }
            p[q*4+0] = pv.x; p[q*4+1] = pv.y; p[q*4+2] = pv.z; p[q*4+3] = pv.w;
            t[q*4+0] = tv.x; t[q*4+1] = tv.y; t[q*4+2] = tv.z; t[q*4+3] = tv.w;
        }

        float hP[8], hT[8], hPP[8], hTT[8], hPT[8];
        #pragma unroll
        for (int o = 0; o < 8; ++o) { hP[o]=0.f; hT[o]=0.f; hPP[o]=0.f; hTT[o]=0.f; hPT[o]=0.f; }
        #pragma unroll
        for (int m = 0; m < 18; ++m) {
            const float pv = p[m + 3], tv = t[m + 3];
            const float pp = pv * pv, tt = tv * tv, pt = pv * tv;
            #pragma unroll
            for (int o = 0; o < 8; ++o) {
                const int k = m - o;            // weight index, compile-time
                if (k >= 0 && k <= 10) {
                    const float wk = w[k];
                    hP [o] = fmaf(wk, pv, hP [o]);
                    hT [o] = fmaf(wk, tv, hT [o]);
                    hPP[o] = fmaf(wk, pp, hPP[o]);
                    hTT[o] = fmaf(wk, tt, hTT[o]);
                    hPT[o] = fmaf(wk, pt, hPT[o]);
                }
            }
        }

        const int x0 = xg << 3;
        *(uint4*)&sPk1[r][x0]     = make_uint4(pack_rtz_u(hP[0], hT[0]), pack_rtz_u(hP[1], hT[1]),
                                               pack_rtz_u(hP[2], hT[2]), pack_rtz_u(hP[3], hT[3]));
        *(uint4*)&sPk1[r][x0 + 4] = make_uint4(pack_rtz_u(hP[4], hT[4]), pack_rtz_u(hP[5], hT[5]),
                                               pack_rtz_u(hP[6], hT[6]), pack_rtz_u(hP[7], hT[7]));
        *(uint4*)&sPk2[r][x0]     = make_uint4(pack_rtz_u(hPP[0], hTT[0]), pack_rtz_u(hPP[1], hTT[1]),
                                               pack_rtz_u(hPP[2], hTT[2]), pack_rtz_u(hPP[3], hTT[3]));
        *(uint4*)&sPk2[r][x0 + 4] = make_uint4(pack_rtz_u(hPP[4], hTT[4]), pack_rtz_u(hPP[5], hTT[5]),
                                               pack_rtz_u(hPP[6], hTT[6]), pack_rtz_u(hPP[7], hTT[7]));
        *(float4*)&sPT[r][x0]     = make_float4(hPT[0], hPT[1], hPT[2], hPT[3]);
        *(float4*)&sPT[r][x0 + 4] = make_float4(hPT[4], hPT[5], hPT[6], hPT[7]);
    }
    __syncthreads();

    // ---- phase 2: packed vertical conv (4-row groups, all 256 threads) ----
    float lsum = 0.0f;
    {
        const int x  = tid & 63;
        const int y0 = (tid >> 6) << 2;   // 0,4,8,12

        h2    acc1[4];
        h2    acc2[4];
        float accPT[4];
        #pragma unroll
        for (int j = 0; j < 4; ++j) {
            acc1[j] = h2{(_Float16)0.f, (_Float16)0.f};
            acc2[j] = h2{(_Float16)0.f, (_Float16)0.f};
            accPT[j] = 0.0f;
        }

        #pragma unroll
        for (int rr = 0; rr < 14; ++rr) {
            const h2    v1 = __builtin_bit_cast(h2, sPk1[y0 + rr][x]);
            const h2    v2 = __builtin_bit_cast(h2, sPk2[y0 + rr][x]);
            const float v3 = sPT[y0 + rr][x];
            #pragma unroll
            for (int j = 0; j < 4; ++j) {
                const int k = rr - j;              // compile-time after unroll
                if (k >= 0 && k <= 10) {
                    acc1[j] = wh[k] * v1 + acc1[j];   // v_pk_fma_f16
                    acc2[j] = wh[k] * v2 + acc2[j];
                    accPT[j] = fmaf(w[k], v3, accPT[j]);
                }
            }
        }

        #pragma unroll
        for (int j = 0; j < 4; ++j) {
            const float mx  = (float)acc1[j][0];
            const float my  = (float)acc1[j][1];
            const float exx = (float)acc2[j][0];
            const float eyy = (float)acc2[j][1];
            const float mxx = mx * mx, myy = my * my, mxy = mx * my;
            const float sx  = exx - mxx;
            const float sy  = eyy - myy;
            const float sxy = accPT[j] - mxy;
            const float num = (2.0f * mxy + 1e-4f) * (2.0f * sxy + 9e-4f);
            const float den = (mxx + myy + 1e-4f) * (sx + sy + 9e-4f);
            lsum = fmaf(num, __builtin_amdgcn_rcpf(den), lsum);
        }
    }

    // ---- block reduction -> one partial per block ----
    #pragma unroll
    for (int off = 32; off > 0; off >>= 1)
        lsum += __shfl_down(lsum, off, 64);
    if ((tid & 63) == 0) sRed[tid >> 6] = lsum;
    __syncthreads();
    if (tid == 0) {
        const int bl = (blockIdx.z * gridDim.y + blockIdx.y) * gridDim.x + blockIdx.x;
        partial[bl] = sRed[0] + sRed[1] + sRed[2] + sRed[3];
    }
}

// ---------------------------------------------------------------------------
// Final reduction: sum partials, out = 1 - mean   (1 block x 1024 threads)
// ---------------------------------------------------------------------------
#define NR 1024
__global__ __launch_bounds__(NR) void ssim_reduce_kernel(
    const float* __restrict__ partial, float* __restrict__ out,
    int n, float inv_npix)
{
    __shared__ float sRed[16];
    float s = 0.0f;
    const int n4 = n >> 2;
    for (int i = threadIdx.x; i < n4; i += NR) {
        const float4 v = ((const float4*)partial)[i];
        s += (v.x + v.y) + (v.z + v.w);
    }
    for (int i = (n4 << 2) + threadIdx.x; i < n; i += NR) s += partial[i];
    #pragma unroll
    for (int off = 32; off > 0; off >>= 1)
        s += __shfl_down(s, off, 64);
    if ((threadIdx.x & 63) == 0) sRed[threadIdx.x >> 6] = s;
    __syncthreads();
    if (threadIdx.x == 0) {
        float tot = 0.0f;
        #pragma unroll
        for (int q = 0; q < 16; ++q) tot += sRed[q];
        out[0] = 1.0f - tot * inv_npix;
    }
}

extern "C" void kernel_launch(void* const* d_in, const int* in_sizes, int n_in,
                              void* d_out, int out_size, void* d_ws, size_t ws_size,
                              hipStream_t stream) {
    const float* pred   = (const float*)d_in[0];
    const float* target = (const float*)d_in[1];
    const float* kern   = (const float*)d_in[2];
    float* out     = (float*)d_out;
    float* partial = (float*)d_ws;   // gx*gy*nimg floats (64 KB here)

    const int nimg = in_sizes[0] / (IMG * IMG);   // 64
    dim3 grid(IMG / TX, IMG / TY, nimg);          // 8 x 32 x 64 = 16384 blocks
    const int nblocks = grid.x * grid.y * grid.z;
    const float inv_npix = 1.0f / ((float)nimg * (float)(IMG * IMG));

    ssim_tile_kernel<<<grid, NT, 0, stream>>>(pred, target, kern, partial);
    ssim_reduce_kernel<<<1, NR, 0, stream>>>(partial, out, nblocks, inv_npix);
}

// Round 5
// 103.055 us; speedup vs baseline: 1.5629x; 1.5629x over previous
//
#include <hip/hip_runtime.h>

#define TX 64        // output tile width
#define TY 16        // output tile height
#define HY 26        // halo height (TY + 10)
#define SHP 68       // sH row stride in elements (64 + 4 pad -> conflict-free)
#define NT 256
#define IMG 512

typedef _Float16 h2 __attribute__((ext_vector_type(2)));

__device__ inline unsigned int pack_rtz_u(float a, float b) {
    auto r = __builtin_amdgcn_cvt_pkrtz(a, b);   // __fp16 ext_vector(2)
    return __builtin_bit_cast(unsigned int, r);
}

// ---------------------------------------------------------------------------
// Fused SSIM tile kernel.
// Phase 1: 208 threads (26 rows x 8 col-groups) read 24 raw px/image from
//          global (aligned float4, zero OOB), horizontal-convolve 8 outputs x
//          5 moment channels, pack (P,T),(PP,TT) to f16x2 + PT f32, write LDS.
// Phase 2: 256 threads (64 cols x 4 row-groups of 4) vertical-convolve with
//          v_pk_fma_f16 (+ f32 for PT), SSIM, block reduce.
// NOTE: launch_bounds min-waves=4 (NOT 7): requesting 7 waves/EU caps VGPR at
// ~73 and the allocator spills p[24]/t[24] to scratch (round 4: 300 MB of
// scratch writes, 161 us). LDS=21.5KB already allows 7 blocks/CU; natural
// VGPR use (~56) allows it too. Don't squeeze the allocator.
// ---------------------------------------------------------------------------
__global__ __launch_bounds__(NT, 4) void ssim_tile_kernel(
    const float* __restrict__ pred,
    const float* __restrict__ target,
    const float* __restrict__ kern,
    float* __restrict__ partial)
{
    __shared__ __align__(16) unsigned int sPk1[HY][SHP];  // f16x2 (P, T)
    __shared__ __align__(16) unsigned int sPk2[HY][SHP];  // f16x2 (PP, TT)
    __shared__ __align__(16) float        sPT [HY][SHP];  // f32 PT
    __shared__ float sRed[4];

    const int tid = threadIdx.x;
    const int tx0 = blockIdx.x * TX;
    const int ty0 = blockIdx.y * TY;
    const int img = blockIdx.z;

    // 1D gaussian weights from center row of the 2D kernel: k2d[5][j] = g5*gj
    float w[11];
    h2    wh[11];
    {
        const float inv_g5 = 1.0f / sqrtf(kern[60]);
        #pragma unroll
        for (int j = 0; j < 11; ++j) {
            w[j] = kern[55 + j] * inv_g5;
            const _Float16 wf = (_Float16)w[j];
            wh[j] = h2{wf, wf};
        }
    }

    // ---- phase 1: global -> registers -> horizontal conv -> packed LDS ----
    if (tid < 208) {
        const int r  = tid >> 3;        // 0..25  (halo row)
        const int xg = tid & 7;         // 0..7   (8-output column group)
        const int gy = ty0 + r - 5;
        const int cb = tx0 + (xg << 3) - 8;   // aligned float4 base
        const bool rowok = (unsigned)gy < IMG;

        const float* prow = pred   + (size_t)img * (IMG * IMG) + gy * IMG;
        const float* trow = target + (size_t)img * (IMG * IMG) + gy * IMG;

        float p[24], t[24];
        #pragma unroll
        for (int q = 0; q < 6; ++q) {
            const int c0 = cb + (q << 2);
            float4 pv = make_float4(0.f, 0.f, 0.f, 0.f);
            float4 tv = make_float4(0.f, 0.f, 0.f, 0.f);
            if (rowok && (unsigned)c0 < IMG) {   // c0 % 4 == 0
                pv = *(const float4*)(prow + c0);
                tv = *(const float4*)(trow + c0);
            }
            p[q*4+0] = pv.x; p[q*4+1] = pv.y; p[q*4+2] = pv.z; p[q*4+3] = pv.w;
            t[q*4+0] = tv.x; t[q*4+1] = tv.y; t[q*4+2] = tv.z; t[q*4+3] = tv.w;
        }

        float hP[8], hT[8], hPP[8], hTT[8], hPT[8];
        #pragma unroll
        for (int o = 0; o < 8; ++o) { hP[o]=0.f; hT[o]=0.f; hPP[o]=0.f; hTT[o]=0.f; hPT[o]=0.f; }
        #pragma unroll
        for (int m = 0; m < 18; ++m) {
            const float pv = p[m + 3], tv = t[m + 3];
            const float pp = pv * pv, tt = tv * tv, pt = pv * tv;
            #pragma unroll
            for (int o = 0; o < 8; ++o) {
                const int k = m - o;            // weight index, compile-time
                if (k >= 0 && k <= 10) {
                    const float wk = w[k];
                    hP [o] = fmaf(wk, pv, hP [o]);
                    hT [o] = fmaf(wk, tv, hT [o]);
                    hPP[o] = fmaf(wk, pp, hPP[o]);
                    hTT[o] = fmaf(wk, tt, hTT[o]);
                    hPT[o] = fmaf(wk, pt, hPT[o]);
                }
            }
        }

        const int x0 = xg << 3;
        *(uint4*)&sPk1[r][x0]     = make_uint4(pack_rtz_u(hP[0], hT[0]), pack_rtz_u(hP[1], hT[1]),
                                               pack_rtz_u(hP[2], hT[2]), pack_rtz_u(hP[3], hT[3]));
        *(uint4*)&sPk1[r][x0 + 4] = make_uint4(pack_rtz_u(hP[4], hT[4]), pack_rtz_u(hP[5], hT[5]),
                                               pack_rtz_u(hP[6], hT[6]), pack_rtz_u(hP[7], hT[7]));
        *(uint4*)&sPk2[r][x0]     = make_uint4(pack_rtz_u(hPP[0], hTT[0]), pack_rtz_u(hPP[1], hTT[1]),
                                               pack_rtz_u(hPP[2], hTT[2]), pack_rtz_u(hPP[3], hTT[3]));
        *(uint4*)&sPk2[r][x0 + 4] = make_uint4(pack_rtz_u(hPP[4], hTT[4]), pack_rtz_u(hPP[5], hTT[5]),
                                               pack_rtz_u(hPP[6], hTT[6]), pack_rtz_u(hPP[7], hTT[7]));
        *(float4*)&sPT[r][x0]     = make_float4(hPT[0], hPT[1], hPT[2], hPT[3]);
        *(float4*)&sPT[r][x0 + 4] = make_float4(hPT[4], hPT[5], hPT[6], hPT[7]);
    }
    __syncthreads();

    // ---- phase 2: packed vertical conv (4-row groups, all 256 threads) ----
    float lsum = 0.0f;
    {
        const int x  = tid & 63;
        const int y0 = (tid >> 6) << 2;   // 0,4,8,12

        h2    acc1[4];
        h2    acc2[4];
        float accPT[4];
        #pragma unroll
        for (int j = 0; j < 4; ++j) {
            acc1[j] = h2{(_Float16)0.f, (_Float16)0.f};
            acc2[j] = h2{(_Float16)0.f, (_Float16)0.f};
            accPT[j] = 0.0f;
        }

        #pragma unroll
        for (int rr = 0; rr < 14; ++rr) {
            const h2    v1 = __builtin_bit_cast(h2, sPk1[y0 + rr][x]);
            const h2    v2 = __builtin_bit_cast(h2, sPk2[y0 + rr][x]);
            const float v3 = sPT[y0 + rr][x];
            #pragma unroll
            for (int j = 0; j < 4; ++j) {
                const int k = rr - j;              // compile-time after unroll
                if (k >= 0 && k <= 10) {
                    acc1[j] = wh[k] * v1 + acc1[j];   // v_pk_fma_f16
                    acc2[j] = wh[k] * v2 + acc2[j];
                    accPT[j] = fmaf(w[k], v3, accPT[j]);
                }
            }
        }

        #pragma unroll
        for (int j = 0; j < 4; ++j) {
            const float mx  = (float)acc1[j][0];
            const float my  = (float)acc1[j][1];
            const float exx = (float)acc2[j][0];
            const float eyy = (float)acc2[j][1];
            const float mxx = mx * mx, myy = my * my, mxy = mx * my;
            const float sx  = exx - mxx;
            const float sy  = eyy - myy;
            const float sxy = accPT[j] - mxy;
            const float num = (2.0f * mxy + 1e-4f) * (2.0f * sxy + 9e-4f);
            const float den = (mxx + myy + 1e-4f) * (sx + sy + 9e-4f);
            lsum = fmaf(num, __builtin_amdgcn_rcpf(den), lsum);
        }
    }

    // ---- block reduction -> one partial per block ----
    #pragma unroll
    for (int off = 32; off > 0; off >>= 1)
        lsum += __shfl_down(lsum, off, 64);
    if ((tid & 63) == 0) sRed[tid >> 6] = lsum;
    __syncthreads();
    if (tid == 0) {
        const int bl = (blockIdx.z * gridDim.y + blockIdx.y) * gridDim.x + blockIdx.x;
        partial[bl] = sRed[0] + sRed[1] + sRed[2] + sRed[3];
    }
}

// ---------------------------------------------------------------------------
// Final reduction: sum partials, out = 1 - mean   (1 block x 1024 threads)
// ---------------------------------------------------------------------------
#define NR 1024
__global__ __launch_bounds__(NR) void ssim_reduce_kernel(
    const float* __restrict__ partial, float* __restrict__ out,
    int n, float inv_npix)
{
    __shared__ float sRed[16];
    float s = 0.0f;
    const int n4 = n >> 2;
    for (int i = threadIdx.x; i < n4; i += NR) {
        const float4 v = ((const float4*)partial)[i];
        s += (v.x + v.y) + (v.z + v.w);
    }
    for (int i = (n4 << 2) + threadIdx.x; i < n; i += NR) s += partial[i];
    #pragma unroll
    for (int off = 32; off > 0; off >>= 1)
        s += __shfl_down(s, off, 64);
    if ((threadIdx.x & 63) == 0) sRed[threadIdx.x >> 6] = s;
    __syncthreads();
    if (threadIdx.x == 0) {
        float tot = 0.0f;
        #pragma unroll
        for (int q = 0; q < 16; ++q) tot += sRed[q];
        out[0] = 1.0f - tot * inv_npix;
    }
}

extern "C" void kernel_launch(void* const* d_in, const int* in_sizes, int n_in,
                              void* d_out, int out_size, void* d_ws, size_t ws_size,
                              hipStream_t stream) {
    const float* pred   = (const float*)d_in[0];
    const float* target = (const float*)d_in[1];
    const float* kern   = (const float*)d_in[2];
    float* out     = (float*)d_out;
    float* partial = (float*)d_ws;   // gx*gy*nimg floats (64 KB here)

    const int nimg = in_sizes[0] / (IMG * IMG);   // 64
    dim3 grid(IMG / TX, IMG / TY, nimg);          // 8 x 32 x 64 = 16384 blocks
    const int nblocks = grid.x * grid.y * grid.z;
    const float inv_npix = 1.0f / ((float)nimg * (float)(IMG * IMG));

    ssim_tile_kernel<<<grid, NT, 0, stream>>>(pred, target, kern, partial);
    ssim_reduce_kernel<<<1, NR, 0, stream>>>(partial, out, nblocks, inv_npix);
}

// Round 6
// 89.984 us; speedup vs baseline: 1.7899x; 1.1453x over previous
//
#include <hip/hip_runtime.h>

#define NT   256
#define IMG  512
#define BT   32     // block output tile: 32x32
#define RAWR 48     // raw moment rows stored (42 valid + zero pad)
#define RAWU 28     // raw row stride in uints (= 56 f16; 112B -> 2-way banks on A-frag reads)
#define HSU  28     // sH col stride in uints (= 56 f16 rows; 112B -> 2-way banks)

typedef _Float16 f16x8 __attribute__((ext_vector_type(8)));
typedef _Float16 h2v   __attribute__((ext_vector_type(2)));
typedef float    f32x4 __attribute__((ext_vector_type(4)));

__device__ inline unsigned pk2(float a, float b) {
    auto r = __builtin_amdgcn_cvt_pkrtz(a, b);     // f32x2 -> f16x2 (RTZ)
    return __builtin_bit_cast(unsigned, r);
}
__device__ inline unsigned pkmul(unsigned a, unsigned b) {
    h2v x = __builtin_bit_cast(h2v, a), y = __builtin_bit_cast(h2v, b);
    h2v z = x * y;                                  // v_pk_mul_f16
    return __builtin_bit_cast(unsigned, z);
}

// ---------------------------------------------------------------------------
// SSIM via MFMA: both separable conv passes are banded matmuls on the f16
// matrix pipe (f32 accumulate), VALU only does moments + SSIM pointwise math.
//   H-conv:  H[m][16ct+n]   = sum_k raw[m][16ct+k] * B1[k][n],  B1[k][n]=w[k-n-3]
//            (the -3 band shift absorbs the 16B-alignment pad of raw staging)
//   V-conv:  out[16rt+r][n] = sum_k A2[r][k] * H[16rt+k][n],    A2[r][k]=w[k-r]
// Fragment maps (gfx950 16x16x32): A: lane&15=m, k=(lane>>4)*8+j (b128 row-major)
//                                  B: lane&15=n, k=(lane>>4)*8+j (b128 col-major store)
//                                  C: col=lane&15, row=(lane>>4)*4+reg (HW-verified)
// ---------------------------------------------------------------------------
__global__ __launch_bounds__(NT) void ssim_mfma_kernel(
    const float* __restrict__ pred,
    const float* __restrict__ target,
    const float* __restrict__ kern,
    float* __restrict__ partial)
{
    __shared__ unsigned sRaw[5][RAWR][RAWU]; // f16 moments P,T,PP,TT,PT; row r<->gy=ty0-5+r, col f16 rc<->gx=tx0-8+rc
    __shared__ unsigned sH[5][BT][HSU];      // h-filtered, COLUMN-major: [col][row pairs]; row hr<->gy=ty0-5+hr
    __shared__ unsigned sB1[16][16];         // B1t[n][k pairs] f16 band (h-conv B operand)
    __shared__ unsigned sA2[16][16];         // A2[r][k pairs]  f16 band (v-conv A operand)
    __shared__ float    wlds[11];
    __shared__ float    sRed[4];

    const int tid = threadIdx.x;
    const int tx0 = blockIdx.x * BT;
    const int ty0 = blockIdx.y * BT;
    const int img = blockIdx.z;

    if (tid < 11) wlds[tid] = kern[55 + tid] * (1.0f / sqrtf(kern[60]));
    __syncthreads();

    // ---- stage raw moments (f16) into LDS: 48 rows x 12 float4-cols ----
    {
        const float* pimg = pred   + (size_t)img * (IMG * IMG);
        const float* timg = target + (size_t)img * (IMG * IMG);
        for (int i = tid; i < RAWR * 12; i += NT) {
            const int r = i / 12;
            const int c = i - r * 12;
            const int gy = ty0 - 5 + r;
            const int gx = tx0 - 8 + 4 * c;
            float4 pv = make_float4(0.f, 0.f, 0.f, 0.f);
            float4 tv = make_float4(0.f, 0.f, 0.f, 0.f);
            if ((unsigned)gy < IMG && (unsigned)gx < IMG) {   // gx % 4 == 0
                const int o = gy * IMG + gx;
                pv = *(const float4*)(pimg + o);
                tv = *(const float4*)(timg + o);
            }
            const unsigned P0 = pk2(pv.x, pv.y), P1 = pk2(pv.z, pv.w);
            const unsigned T0 = pk2(tv.x, tv.y), T1 = pk2(tv.z, tv.w);
            const int u = 2 * c;
            *(uint2*)&sRaw[0][r][u] = make_uint2(P0, P1);
            *(uint2*)&sRaw[1][r][u] = make_uint2(T0, T1);
            *(uint2*)&sRaw[2][r][u] = make_uint2(pkmul(P0, P0), pkmul(P1, P1));
            *(uint2*)&sRaw[3][r][u] = make_uint2(pkmul(T0, T0), pkmul(T1, T1));
            *(uint2*)&sRaw[4][r][u] = make_uint2(pkmul(P0, T0), pkmul(P1, T1));
        }
    }

    // ---- build band matrices from w (each thread 1 f16-pair of each) ----
    {
        const int n  = tid >> 4;          // 0..15 (n for B1, r for A2)
        const int kp = tid & 15;          // k-pair index, k = 2*kp
        const int k  = kp * 2;
        float b0 = 0.f, b1 = 0.f, a0 = 0.f, a1 = 0.f;
        const int d0 = k - n - 3;
        if ((unsigned)d0 <= 10u)       b0 = wlds[d0];
        if ((unsigned)(d0 + 1) <= 10u) b1 = wlds[d0 + 1];
        const int e0 = k - n;
        if ((unsigned)e0 <= 10u)       a0 = wlds[e0];
        if ((unsigned)(e0 + 1) <= 10u) a1 = wlds[e0 + 1];
        sB1[n][kp] = pk2(b0, b1);
        sA2[n][kp] = pk2(a0, a1);
    }
    __syncthreads();

    const int lane = tid & 63;
    const int wv   = tid >> 6;
    const int lm   = lane & 15;     // m (A row) / n (B col) / C col
    const int lg   = lane >> 4;     // k-group; C row-group

    const f16x8 bfrag  = __builtin_bit_cast(f16x8, *(const uint4*)&sB1[lm][4 * lg]);
    const f16x8 a2frag = __builtin_bit_cast(f16x8, *(const uint4*)&sA2[lm][4 * lg]);
    const f32x4 zero4 = {0.f, 0.f, 0.f, 0.f};

    // ---- H-conv: 30 mfma jobs (3 row-tiles x 2 col-tiles x 5 channels) ----
    for (int j = wv; j < 30; j += 4) {
        const int ch = j % 5;
        const int g2 = j / 5;
        const int ct = g2 & 1;
        const int mt = g2 >> 1;
        const f16x8 afrag = __builtin_bit_cast(f16x8,
            *(const uint4*)&sRaw[ch][mt * 16 + lm][8 * ct + 4 * lg]);
        const f32x4 h = __builtin_amdgcn_mfma_f32_16x16x32_f16(afrag, bfrag, zero4, 0, 0, 0);
        // C elem (row = mt*16 + 4*lg + reg, col = 16*ct + lm) -> sH column-major
        *(uint2*)&sH[ch][16 * ct + lm][mt * 8 + 2 * lg] =
            make_uint2(pk2(h[0], h[1]), pk2(h[2], h[3]));
    }
    __syncthreads();

    // ---- V-conv: each wave one 16x16 output quadrant, 5 channels ----
    const int rt  = wv >> 1;
    const int ct2 = wv & 1;
    f32x4 M[5];
    #pragma unroll
    for (int ch = 0; ch < 5; ++ch) {
        const f16x8 b2 = __builtin_bit_cast(f16x8,
            *(const uint4*)&sH[ch][16 * ct2 + lm][8 * rt + 4 * lg]);
        M[ch] = __builtin_amdgcn_mfma_f32_16x16x32_f16(a2frag, b2, zero4, 0, 0, 0);
    }

    // ---- SSIM pointwise + block reduction ----
    float lsum = 0.f;
    #pragma unroll
    for (int r = 0; r < 4; ++r) {
        const float mx = M[0][r], my = M[1][r];
        const float exx = M[2][r], eyy = M[3][r], exy = M[4][r];
        const float mxx = mx * mx, myy = my * my, mxy = mx * my;
        const float sx  = exx - mxx;
        const float sy  = eyy - myy;
        const float sxy = exy - mxy;
        const float num = (2.0f * mxy + 1e-4f) * (2.0f * sxy + 9e-4f);
        const float den = (mxx + myy + 1e-4f) * (sx + sy + 9e-4f);
        lsum = fmaf(num, __builtin_amdgcn_rcpf(den), lsum);
    }
    #pragma unroll
    for (int off = 32; off > 0; off >>= 1)
        lsum += __shfl_down(lsum, off, 64);
    if (lane == 0) sRed[wv] = lsum;
    __syncthreads();
    if (tid == 0) {
        const int bl = (img * gridDim.y + blockIdx.y) * gridDim.x + blockIdx.x;
        partial[bl] = sRed[0] + sRed[1] + sRed[2] + sRed[3];
    }
}

// ---------------------------------------------------------------------------
// Final reduction: sum partials, out = 1 - mean   (1 block x 1024 threads)
// ---------------------------------------------------------------------------
#define NR 1024
__global__ __launch_bounds__(NR) void ssim_reduce_kernel(
    const float* __restrict__ partial, float* __restrict__ out,
    int n, float inv_npix)
{
    __shared__ float sRed[16];
    float s = 0.0f;
    const int n4 = n >> 2;
    for (int i = threadIdx.x; i < n4; i += NR) {
        const float4 v = ((const float4*)partial)[i];
        s += (v.x + v.y) + (v.z + v.w);
    }
    for (int i = (n4 << 2) + threadIdx.x; i < n; i += NR) s += partial[i];
    #pragma unroll
    for (int off = 32; off > 0; off >>= 1)
        s += __shfl_down(s, off, 64);
    if ((threadIdx.x & 63) == 0) sRed[threadIdx.x >> 6] = s;
    __syncthreads();
    if (threadIdx.x == 0) {
        float tot = 0.0f;
        #pragma unroll
        for (int q = 0; q < 16; ++q) tot += sRed[q];
        out[0] = 1.0f - tot * inv_npix;
    }
}

extern "C" void kernel_launch(void* const* d_in, const int* in_sizes, int n_in,
                              void* d_out, int out_size, void* d_ws, size_t ws_size,
                              hipStream_t stream) {
    const float* pred   = (const float*)d_in[0];
    const float* target = (const float*)d_in[1];
    const float* kern   = (const float*)d_in[2];
    float* out     = (float*)d_out;
    float* partial = (float*)d_ws;   // 16*16*64 = 16384 floats = 64 KB

    const int nimg = in_sizes[0] / (IMG * IMG);   // 64
    dim3 grid(IMG / BT, IMG / BT, nimg);          // 16 x 16 x 64 = 16384 blocks
    const int nblocks = grid.x * grid.y * grid.z;
    const float inv_npix = 1.0f / ((float)nimg * (float)(IMG * IMG));

    ssim_mfma_kernel<<<grid, NT, 0, stream>>>(pred, target, kern, partial);
    ssim_reduce_kernel<<<1, NR, 0, stream>>>(partial, out, nblocks, inv_npix);
}

// Round 7
// 68.855 us; speedup vs baseline: 2.3392x; 1.3069x over previous
//
#include <hip/hip_runtime.h>

#define NT   256
#define IMG  512
#define BT   32     // block output tile: 32x32
#define RAWR 48     // raw rows stored (42 valid + zero pad)
#define RAWU 28     // raw row stride in uints (56 f16; 112B)
#define HSU  28     // sH col stride in uints (56 f16 rows; 112B)

typedef _Float16 f16x8 __attribute__((ext_vector_type(8)));
typedef float    f32x4 __attribute__((ext_vector_type(4)));

__device__ inline unsigned pk2(float a, float b) {
    auto r = __builtin_amdgcn_cvt_pkrtz(a, b);     // f32x2 -> f16x2 (RTZ)
    return __builtin_bit_cast(unsigned, r);
}

// ---------------------------------------------------------------------------
// SSIM via MFMA, v2: stage only raw P,T (f16) in LDS; the PP/TT/PT MFMA
// A-fragments are derived in-register as elementwise products of the P/T
// fragments (identical values to staging them — conv is linear, moments are
// pointwise). Cuts LDS 46->31 KB (3->5 blocks/CU) and staging VALU/ds_writes.
//   H-conv:  H[m][16ct+n]   = sum_k raw[m][16ct+k] * B1[k][n],  B1[k][n]=w[k-n-3]
//   V-conv:  out[16rt+r][n] = sum_k A2[r][k] * H[16rt+k][n],    A2[r][k]=w[k-r]
// Fragment maps (gfx950 16x16x32, validated round 6 via absmax):
//   A: lane&15=m, k=(lane>>4)*8+j | B: lane&15=n, same k | C: col=lane&15,
//   row=(lane>>4)*4+reg.
// launch_bounds(256,4): do NOT squeeze higher — round 4 showed the allocator
// spills to scratch (300 MB of writes) when capped below natural VGPR use.
// ---------------------------------------------------------------------------
__global__ __launch_bounds__(NT, 4) void ssim_mfma_kernel(
    const float* __restrict__ pred,
    const float* __restrict__ target,
    const float* __restrict__ kern,
    float* __restrict__ partial)
{
    __shared__ unsigned sRaw[2][RAWR][RAWU]; // f16 raw P,T; row r<->gy=ty0-5+r, f16 col rc<->gx=tx0-8+rc
    __shared__ unsigned sH[5][BT][HSU];      // h-filtered, column-major [col][row pairs]; row hr<->gy=ty0-5+hr
    __shared__ unsigned sB1[16][16];         // B1t[n][k pairs] f16 band (h-conv B operand)
    __shared__ unsigned sA2[16][16];         // A2[r][k pairs]  f16 band (v-conv A operand)
    __shared__ float    wlds[11];
    __shared__ float    sRed[4];

    const int tid = threadIdx.x;
    const int tx0 = blockIdx.x * BT;
    const int ty0 = blockIdx.y * BT;
    const int img = blockIdx.z;

    if (tid < 11) wlds[tid] = kern[55 + tid] * (1.0f / sqrtf(kern[60]));
    __syncthreads();

    // ---- stage raw P,T (f16) into LDS: 48 rows x 6 groups of 8 px ----
    {
        const float* pimg = pred   + (size_t)img * (IMG * IMG);
        const float* timg = target + (size_t)img * (IMG * IMG);
        for (int i = tid; i < RAWR * 6; i += NT) {
            const int r = i / 6;
            const int c = i - r * 6;
            const int gy = ty0 - 5 + r;
            const int gx = tx0 - 8 + 8 * c;
            float4 p0 = make_float4(0.f,0.f,0.f,0.f), p1 = p0, t0 = p0, t1 = p0;
            if ((unsigned)gy < IMG) {
                const float* prow = pimg + gy * IMG;
                const float* trow = timg + gy * IMG;
                if ((unsigned)gx < IMG) {          // gx % 4 == 0
                    p0 = *(const float4*)(prow + gx);
                    t0 = *(const float4*)(trow + gx);
                }
                if ((unsigned)(gx + 4) < IMG) {
                    p1 = *(const float4*)(prow + gx + 4);
                    t1 = *(const float4*)(trow + gx + 4);
                }
            }
            const int u = 4 * c;
            *(uint4*)&sRaw[0][r][u] = make_uint4(pk2(p0.x,p0.y), pk2(p0.z,p0.w),
                                                 pk2(p1.x,p1.y), pk2(p1.z,p1.w));
            *(uint4*)&sRaw[1][r][u] = make_uint4(pk2(t0.x,t0.y), pk2(t0.z,t0.w),
                                                 pk2(t1.x,t1.y), pk2(t1.z,t1.w));
        }
    }

    // ---- build band matrices from w (each thread 1 f16-pair of each) ----
    {
        const int n  = tid >> 4;          // 0..15 (n for B1, r for A2)
        const int kp = tid & 15;          // k-pair index, k = 2*kp
        const int k  = kp * 2;
        float b0 = 0.f, b1 = 0.f, a0 = 0.f, a1 = 0.f;
        const int d0 = k - n - 3;
        if ((unsigned)d0 <= 10u)       b0 = wlds[d0];
        if ((unsigned)(d0 + 1) <= 10u) b1 = wlds[d0 + 1];
        const int e0 = k - n;
        if ((unsigned)e0 <= 10u)       a0 = wlds[e0];
        if ((unsigned)(e0 + 1) <= 10u) a1 = wlds[e0 + 1];
        sB1[n][kp] = pk2(b0, b1);
        sA2[n][kp] = pk2(a0, a1);
    }
    __syncthreads();

    const int lane = tid & 63;
    const int wv   = tid >> 6;
    const int lm   = lane & 15;     // m (A row) / n (B col) / C col
    const int lg   = lane >> 4;     // k-group; C row-group

    const f16x8 bfrag  = __builtin_bit_cast(f16x8, *(const uint4*)&sB1[lm][4 * lg]);
    const f16x8 a2frag = __builtin_bit_cast(f16x8, *(const uint4*)&sA2[lm][4 * lg]);
    const f32x4 zero4 = {0.f, 0.f, 0.f, 0.f};

    // ---- H-conv: 6 position jobs (3 row-tiles x 2 col-tiles) x 5 channels ----
    for (int j = wv; j < 6; j += 4) {
        const int ct = j & 1;
        const int mt = j >> 1;
        const f16x8 aP = __builtin_bit_cast(f16x8,
            *(const uint4*)&sRaw[0][mt * 16 + lm][8 * ct + 4 * lg]);
        const f16x8 aT = __builtin_bit_cast(f16x8,
            *(const uint4*)&sRaw[1][mt * 16 + lm][8 * ct + 4 * lg]);
        f16x8 af[5];
        af[0] = aP; af[1] = aT;
        af[2] = aP * aP;                 // 4x v_pk_mul_f16 each
        af[3] = aT * aT;
        af[4] = aP * aT;
        #pragma unroll
        for (int ch = 0; ch < 5; ++ch) {
            const f32x4 h = __builtin_amdgcn_mfma_f32_16x16x32_f16(af[ch], bfrag, zero4, 0, 0, 0);
            // C elem (row = mt*16 + 4*lg + reg, col = 16*ct + lm) -> sH col-major
            *(uint2*)&sH[ch][16 * ct + lm][mt * 8 + 2 * lg] =
                make_uint2(pk2(h[0], h[1]), pk2(h[2], h[3]));
        }
    }
    __syncthreads();

    // ---- V-conv: each wave one 16x16 output quadrant, 5 channels ----
    const int rt  = wv >> 1;
    const int ct2 = wv & 1;
    f32x4 M[5];
    #pragma unroll
    for (int ch = 0; ch < 5; ++ch) {
        const f16x8 b2 = __builtin_bit_cast(f16x8,
            *(const uint4*)&sH[ch][16 * ct2 + lm][8 * rt + 4 * lg]);
        M[ch] = __builtin_amdgcn_mfma_f32_16x16x32_f16(a2frag, b2, zero4, 0, 0, 0);
    }

    // ---- SSIM pointwise + block reduction ----
    float lsum = 0.f;
    #pragma unroll
    for (int r = 0; r < 4; ++r) {
        const float mx = M[0][r], my = M[1][r];
        const float exx = M[2][r], eyy = M[3][r], exy = M[4][r];
        const float mxx = mx * mx, myy = my * my, mxy = mx * my;
        const float sx  = exx - mxx;
        const float sy  = eyy - myy;
        const float sxy = exy - mxy;
        const float num = (2.0f * mxy + 1e-4f) * (2.0f * sxy + 9e-4f);
        const float den = (mxx + myy + 1e-4f) * (sx + sy + 9e-4f);
        lsum = fmaf(num, __builtin_amdgcn_rcpf(den), lsum);
    }
    #pragma unroll
    for (int off = 32; off > 0; off >>= 1)
        lsum += __shfl_down(lsum, off, 64);
    if (lane == 0) sRed[wv] = lsum;
    __syncthreads();
    if (tid == 0) {
        const int bl = (img * gridDim.y + blockIdx.y) * gridDim.x + blockIdx.x;
        partial[bl] = sRed[0] + sRed[1] + sRed[2] + sRed[3];
    }
}

// ---------------------------------------------------------------------------
// Final reduction: sum partials, out = 1 - mean   (1 block x 1024 threads)
// ---------------------------------------------------------------------------
#define NR 1024
__global__ __launch_bounds__(NR) void ssim_reduce_kernel(
    const float* __restrict__ partial, float* __restrict__ out,
    int n, float inv_npix)
{
    __shared__ float sRed[16];
    float s = 0.0f;
    const int n4 = n >> 2;
    for (int i = threadIdx.x; i < n4; i += NR) {
        const float4 v = ((const float4*)partial)[i];
        s += (v.x + v.y) + (v.z + v.w);
    }
    for (int i = (n4 << 2) + threadIdx.x; i < n; i += NR) s += partial[i];
    #pragma unroll
    for (int off = 32; off > 0; off >>= 1)
        s += __shfl_down(s, off, 64);
    if ((threadIdx.x & 63) == 0) sRed[threadIdx.x >> 6] = s;
    __syncthreads();
    if (threadIdx.x == 0) {
        float tot = 0.0f;
        #pragma unroll
        for (int q = 0; q < 16; ++q) tot += sRed[q];
        out[0] = 1.0f - tot * inv_npix;
    }
}

extern "C" void kernel_launch(void* const* d_in, const int* in_sizes, int n_in,
                              void* d_out, int out_size, void* d_ws, size_t ws_size,
                              hipStream_t stream) {
    const float* pred   = (const float*)d_in[0];
    const float* target = (const float*)d_in[1];
    const float* kern   = (const float*)d_in[2];
    float* out     = (float*)d_out;
    float* partial = (float*)d_ws;   // 16*16*64 = 16384 floats = 64 KB

    const int nimg = in_sizes[0] / (IMG * IMG);   // 64
    dim3 grid(IMG / BT, IMG / BT, nimg);          // 16 x 16 x 64 = 16384 blocks
    const int nblocks = grid.x * grid.y * grid.z;
    const float inv_npix = 1.0f / ((float)nimg * (float)(IMG * IMG));

    ssim_mfma_kernel<<<grid, NT, 0, stream>>>(pred, target, kern, partial);
    ssim_reduce_kernel<<<1, NR, 0, stream>>>(partial, out, nblocks, inv_npix);
}

// Round 8
// 58.496 us; speedup vs baseline: 2.7534x; 1.1771x over previous
//
#include <hip/hip_runtime.h>

#define NT   256
#define IMG  512
#define BT   32     // block output tile: 32x32
#define RAWR 48     // raw rows stored (42 valid + zero pad)
#define RAWU 28     // raw row stride in uints (56 f16; 112B -> 2-way banks)
#define HSU  28     // sH col stride in uints (112B -> 2-way banks)

typedef _Float16 f16x8 __attribute__((ext_vector_type(8)));
typedef float    f32x4 __attribute__((ext_vector_type(4)));

__device__ inline unsigned pk2(float a, float b) {
    auto r = __builtin_amdgcn_cvt_pkrtz(a, b);     // f32x2 -> f16x2 (RTZ)
    return __builtin_bit_cast(unsigned, r);
}

// ---------------------------------------------------------------------------
// SSIM via MFMA, v3. Changes vs v2 (69 us):
//  - LDS union: sH overwrites sRaw after H-conv A-frags are prefetched to
//    registers (extra barrier). LDS 31.2 -> 17.9 KB => up to 8 blocks/CU.
//  - Band fragments (B1/A2) computed per-lane straight from kern (L1-hit
//    scalar loads) - no band LDS, one fewer sync phase.
//  - Bijective XCD swizzle on a flat 1D grid: each XCD owns 8 contiguous
//    images, so horizontally-adjacent tiles share halo lines in its L2.
// Math identical to v2 (absmax 0.0039 verified):
//   H-conv:  H[m][16ct+n]   = sum_k raw[m][16ct+k] * B1[k][n],  B1[k][n]=w[k-n-3]
//   V-conv:  out[16rt+r][n] = sum_k A2[r][k] * H[16rt+k][n],    A2[r][k]=w[k-r]
//   PP/TT/PT A-frags derived in-register as elementwise products of P/T frags.
// Fragment maps (gfx950 16x16x32): A: lane&15=m, k=(lane>>4)*8+j | B: lane&15=n,
//   same k | C: col=lane&15, row=(lane>>4)*4+reg.
// launch_bounds(256,4): round 4 showed squeezing further spills to scratch.
// ---------------------------------------------------------------------------
__global__ __launch_bounds__(NT, 4) void ssim_mfma_kernel(
    const float* __restrict__ pred,
    const float* __restrict__ target,
    const float* __restrict__ kern,
    float* __restrict__ partial)
{
    __shared__ __align__(16) unsigned sMem[5 * BT * HSU];  // 17.9 KB union
    __shared__ float sRed[4];

    typedef unsigned (*RawPtr)[RAWR][RAWU];   // [2][48][28] = 10.75 KB (head of sMem)
    typedef unsigned (*HPtr)[BT][HSU];        // [5][32][28] = 17.9 KB (all of sMem)
    RawPtr sRaw = (RawPtr)sMem;
    HPtr   sH   = (HPtr)sMem;

    const int tid = threadIdx.x;

    // ---- bijective XCD swizzle (gridDim.x % 8 == 0): XCD -> 8 whole images ----
    const int bid   = blockIdx.x;
    const int chunk = (int)gridDim.x >> 3;
    const int swz   = (bid & 7) * chunk + (bid >> 3);
    const int img   = swz >> 8;               // 256 tiles per 512x512 image
    const int rem   = swz & 255;
    const int tx0   = (rem & 15) * BT;
    const int ty0   = (rem >> 4) * BT;

    const int lane = tid & 63;
    const int wv   = tid >> 6;
    const int lm   = lane & 15;     // m (A row) / n (B col) / C col
    const int lg   = lane >> 4;     // k-group; C row-group

    // ---- band fragments straight from kern (per-lane, L1-resident) ----
    unsigned bu[4], au[4];
    {
        const float invg = 1.0f / sqrtf(kern[60]);
        #pragma unroll
        for (int jp = 0; jp < 4; ++jp) {
            const int k0 = 8 * lg + 2 * jp;
            const int d  = k0 - lm - 3;        // B1 band: w[k-n-3]
            const int e  = k0 - lm;            // A2 band: w[k-r]
            float b0 = 0.f, b1 = 0.f, a0 = 0.f, a1 = 0.f;
            if ((unsigned)d       <= 10u) b0 = kern[55 + d] * invg;
            if ((unsigned)(d + 1) <= 10u) b1 = kern[56 + d] * invg;
            if ((unsigned)e       <= 10u) a0 = kern[55 + e] * invg;
            if ((unsigned)(e + 1) <= 10u) a1 = kern[56 + e] * invg;
            bu[jp] = pk2(b0, b1);
            au[jp] = pk2(a0, a1);
        }
    }
    const f16x8 bfrag  = __builtin_bit_cast(f16x8, make_uint4(bu[0], bu[1], bu[2], bu[3]));
    const f16x8 a2frag = __builtin_bit_cast(f16x8, make_uint4(au[0], au[1], au[2], au[3]));
    const f32x4 zero4  = {0.f, 0.f, 0.f, 0.f};

    // ---- stage raw P,T (f16) into LDS: 48 rows x 6 groups of 8 px ----
    {
        const float* pimg = pred   + (size_t)img * (IMG * IMG);
        const float* timg = target + (size_t)img * (IMG * IMG);
        for (int i = tid; i < RAWR * 6; i += NT) {
            const int r  = i / 6;
            const int c  = i - r * 6;
            const int gy = ty0 - 5 + r;
            const int gx = tx0 - 8 + 8 * c;
            float4 p0 = make_float4(0.f, 0.f, 0.f, 0.f), p1 = p0, t0 = p0, t1 = p0;
            if ((unsigned)gy < IMG) {
                const float* prow = pimg + gy * IMG;
                const float* trow = timg + gy * IMG;
                if ((unsigned)gx < IMG) {          // gx % 4 == 0
                    p0 = *(const float4*)(prow + gx);
                    t0 = *(const float4*)(trow + gx);
                }
                if ((unsigned)(gx + 4) < IMG) {
                    p1 = *(const float4*)(prow + gx + 4);
                    t1 = *(const float4*)(trow + gx + 4);
                }
            }
            const int u = 4 * c;
            *(uint4*)&sRaw[0][r][u] = make_uint4(pk2(p0.x, p0.y), pk2(p0.z, p0.w),
                                                 pk2(p1.x, p1.y), pk2(p1.z, p1.w));
            *(uint4*)&sRaw[1][r][u] = make_uint4(pk2(t0.x, t0.y), pk2(t0.z, t0.w),
                                                 pk2(t1.x, t1.y), pk2(t1.z, t1.w));
        }
    }
    __syncthreads();

    // ---- prefetch H-conv A-frags to registers (sH will overwrite sRaw) ----
    // jobs: j = wv (ct=wv&1, mt=wv>>1); j = wv+4 for wv<2 (ct=wv, mt=2)
    const int ct0 = wv & 1, mt0 = wv >> 1;
    f16x8 aP0 = __builtin_bit_cast(f16x8, *(const uint4*)&sRaw[0][mt0 * 16 + lm][8 * ct0 + 4 * lg]);
    f16x8 aT0 = __builtin_bit_cast(f16x8, *(const uint4*)&sRaw[1][mt0 * 16 + lm][8 * ct0 + 4 * lg]);
    f16x8 aP1 = aP0, aT1 = aT0;
    if (wv < 2) {
        aP1 = __builtin_bit_cast(f16x8, *(const uint4*)&sRaw[0][32 + lm][8 * wv + 4 * lg]);
        aT1 = __builtin_bit_cast(f16x8, *(const uint4*)&sRaw[1][32 + lm][8 * wv + 4 * lg]);
    }
    __syncthreads();   // all raw reads done; safe to overwrite with sH

    // ---- H-conv: mfma per channel, write h-filtered (f16) column-major ----
    {
        f16x8 af[5];
        af[0] = aP0; af[1] = aT0;
        af[2] = aP0 * aP0;                 // 4x v_pk_mul_f16 each
        af[3] = aT0 * aT0;
        af[4] = aP0 * aT0;
        #pragma unroll
        for (int ch = 0; ch < 5; ++ch) {
            const f32x4 h = __builtin_amdgcn_mfma_f32_16x16x32_f16(af[ch], bfrag, zero4, 0, 0, 0);
            *(uint2*)&sH[ch][16 * ct0 + lm][mt0 * 8 + 2 * lg] =
                make_uint2(pk2(h[0], h[1]), pk2(h[2], h[3]));
        }
    }
    if (wv < 2) {
        f16x8 af[5];
        af[0] = aP1; af[1] = aT1;
        af[2] = aP1 * aP1;
        af[3] = aT1 * aT1;
        af[4] = aP1 * aT1;
        #pragma unroll
        for (int ch = 0; ch < 5; ++ch) {
            const f32x4 h = __builtin_amdgcn_mfma_f32_16x16x32_f16(af[ch], bfrag, zero4, 0, 0, 0);
            *(uint2*)&sH[ch][16 * wv + lm][2 * 8 + 2 * lg] =
                make_uint2(pk2(h[0], h[1]), pk2(h[2], h[3]));
        }
    }
    __syncthreads();

    // ---- V-conv: each wave one 16x16 output quadrant, 5 channels ----
    const int rt  = wv >> 1;
    const int ct2 = wv & 1;
    f32x4 M[5];
    #pragma unroll
    for (int ch = 0; ch < 5; ++ch) {
        const f16x8 b2 = __builtin_bit_cast(f16x8,
            *(const uint4*)&sH[ch][16 * ct2 + lm][8 * rt + 4 * lg]);
        M[ch] = __builtin_amdgcn_mfma_f32_16x16x32_f16(a2frag, b2, zero4, 0, 0, 0);
    }

    // ---- SSIM pointwise + block reduction ----
    float lsum = 0.f;
    #pragma unroll
    for (int r = 0; r < 4; ++r) {
        const float mx = M[0][r], my = M[1][r];
        const float exx = M[2][r], eyy = M[3][r], exy = M[4][r];
        const float mxx = mx * mx, myy = my * my, mxy = mx * my;
        const float sx  = exx - mxx;
        const float sy  = eyy - myy;
        const float sxy = exy - mxy;
        const float num = (2.0f * mxy + 1e-4f) * (2.0f * sxy + 9e-4f);
        const float den = (mxx + myy + 1e-4f) * (sx + sy + 9e-4f);
        lsum = fmaf(num, __builtin_amdgcn_rcpf(den), lsum);
    }
    #pragma unroll
    for (int off = 32; off > 0; off >>= 1)
        lsum += __shfl_down(lsum, off, 64);
    if (lane == 0) sRed[wv] = lsum;
    __syncthreads();
    if (tid == 0)
        partial[bid] = sRed[0] + sRed[1] + sRed[2] + sRed[3];
}

// ---------------------------------------------------------------------------
// Final reduction: sum partials, out = 1 - mean   (1 block x 1024 threads)
// ---------------------------------------------------------------------------
#define NR 1024
__global__ __launch_bounds__(NR) void ssim_reduce_kernel(
    const float* __restrict__ partial, float* __restrict__ out,
    int n, float inv_npix)
{
    __shared__ float sRed[16];
    float s = 0.0f;
    const int n4 = n >> 2;
    for (int i = threadIdx.x; i < n4; i += NR) {
        const float4 v = ((const float4*)partial)[i];
        s += (v.x + v.y) + (v.z + v.w);
    }
    for (int i = (n4 << 2) + threadIdx.x; i < n; i += NR) s += partial[i];
    #pragma unroll
    for (int off = 32; off > 0; off >>= 1)
        s += __shfl_down(s, off, 64);
    if ((threadIdx.x & 63) == 0) sRed[threadIdx.x >> 6] = s;
    __syncthreads();
    if (threadIdx.x == 0) {
        float tot = 0.0f;
        #pragma unroll
        for (int q = 0; q < 16; ++q) tot += sRed[q];
        out[0] = 1.0f - tot * inv_npix;
    }
}

extern "C" void kernel_launch(void* const* d_in, const int* in_sizes, int n_in,
                              void* d_out, int out_size, void* d_ws, size_t ws_size,
                              hipStream_t stream) {
    const float* pred   = (const float*)d_in[0];
    const float* target = (const float*)d_in[1];
    const float* kern   = (const float*)d_in[2];
    float* out     = (float*)d_out;
    float* partial = (float*)d_ws;   // 256*nimg floats (64 KB here)

    const int nimg    = in_sizes[0] / (IMG * IMG);          // 64
    const int nblocks = (IMG / BT) * (IMG / BT) * nimg;     // 16384 (mult of 8)
    const float inv_npix = 1.0f / ((float)nimg * (float)(IMG * IMG));

    ssim_mfma_kernel<<<dim3(nblocks), NT, 0, stream>>>(pred, target, kern, partial);
    ssim_reduce_kernel<<<1, NR, 0, stream>>>(partial, out, nblocks, inv_npix);
}

// Round 9
// 44.837 us; speedup vs baseline: 3.5922x; 1.3047x over previous
//
#include <hip/hip_runtime.h>

#define NT   256
#define IMG  512
#define BT   32     // block output tile: 32x32
#define RAWR 48     // raw rows stored (42 valid + zero pad)
#define RAWU 28     // raw row stride in uints (56 f16; 112B -> 2-way banks)
#define HSU  28     // sH col stride in uints (112B -> 2-way banks)
#define WS_PARTIAL_OFF 1024   // floats; band table occupies first 2KB of ws

typedef _Float16 f16x8 __attribute__((ext_vector_type(8)));
typedef float    f32x4 __attribute__((ext_vector_type(4)));

__device__ inline unsigned pk2(float a, float b) {
    auto r = __builtin_amdgcn_cvt_pkrtz(a, b);     // f32x2 -> f16x2 (RTZ)
    return __builtin_bit_cast(unsigned, r);
}

// ---------------------------------------------------------------------------
// One-time init: per-lane MFMA band fragments for both conv passes -> ws.
// tab[l*8+0..3] = B1 frag (h-conv B operand), tab[l*8+4..7] = A2 frag.
// Same arithmetic as computing in-block (bit-identical results).
// ---------------------------------------------------------------------------
__global__ void ssim_init_kernel(const float* __restrict__ kern,
                                 unsigned* __restrict__ tab) {
    const int l  = threadIdx.x;        // 0..63
    const int lm = l & 15;
    const int lg = l >> 4;
    const float invg = 1.0f / sqrtf(kern[60]);
    unsigned bu[4], au[4];
    #pragma unroll
    for (int jp = 0; jp < 4; ++jp) {
        const int k0 = 8 * lg + 2 * jp;
        const int d  = k0 - lm - 3;        // B1 band: w[k-n-3]
        const int e  = k0 - lm;            // A2 band: w[k-r]
        float b0 = 0.f, b1 = 0.f, a0 = 0.f, a1 = 0.f;
        if ((unsigned)d       <= 10u) b0 = kern[55 + d] * invg;
        if ((unsigned)(d + 1) <= 10u) b1 = kern[56 + d] * invg;
        if ((unsigned)e       <= 10u) a0 = kern[55 + e] * invg;
        if ((unsigned)(e + 1) <= 10u) a1 = kern[56 + e] * invg;
        bu[jp] = pk2(b0, b1);
        au[jp] = pk2(a0, a1);
    }
    *(uint4*)&tab[l * 8]     = make_uint4(bu[0], bu[1], bu[2], bu[3]);
    *(uint4*)&tab[l * 8 + 4] = make_uint4(au[0], au[1], au[2], au[3]);
}

// ---------------------------------------------------------------------------
// SSIM via MFMA, v4. Changes vs v3 (58.5 us):
//  - band fragments loaded from the precomputed ws table (2x dwordx4, L2-hit)
//    instead of ~80 VALU + 16 predicated kern loads per lane per block.
//  - interior blocks (77%) take an unpredicated staging fast path.
// Math identical to v2/v3 (absmax 0.0039):
//   H-conv:  H[m][16ct+n]   = sum_k raw[m][16ct+k] * B1[k][n],  B1[k][n]=w[k-n-3]
//   V-conv:  out[16rt+r][n] = sum_k A2[r][k] * H[16rt+k][n],    A2[r][k]=w[k-r]
//   PP/TT/PT A-frags derived in-register as products of P/T frags.
// Fragment maps (gfx950 16x16x32): A: lane&15=m, k=(lane>>4)*8+j | B: lane&15=n,
//   same k | C: col=lane&15, row=(lane>>4)*4+reg.
// launch_bounds(256,4): round 4 showed squeezing further spills to scratch.
// ---------------------------------------------------------------------------
__global__ __launch_bounds__(NT, 4) void ssim_mfma_kernel(
    const float* __restrict__ pred,
    const float* __restrict__ target,
    const unsigned* __restrict__ tab,
    float* __restrict__ partial)
{
    __shared__ __align__(16) unsigned sMem[5 * BT * HSU];  // 17.9 KB union
    __shared__ float sRed[4];

    typedef unsigned (*RawPtr)[RAWR][RAWU];   // [2][48][28] head of sMem
    typedef unsigned (*HPtr)[BT][HSU];        // [5][32][28] all of sMem
    RawPtr sRaw = (RawPtr)sMem;
    HPtr   sH   = (HPtr)sMem;

    const int tid = threadIdx.x;

    // ---- bijective XCD swizzle (gridDim.x % 8 == 0): XCD -> 8 whole images ----
    const int bid   = blockIdx.x;
    const int chunk = (int)gridDim.x >> 3;
    const int swz   = (bid & 7) * chunk + (bid >> 3);
    const int img   = swz >> 8;               // 256 tiles per 512x512 image
    const int rem   = swz & 255;
    const int tx0   = (rem & 15) * BT;
    const int ty0   = (rem >> 4) * BT;

    const int lane = tid & 63;
    const int wv   = tid >> 6;
    const int lm   = lane & 15;     // m (A row) / n (B col) / C col
    const int lg   = lane >> 4;     // k-group; C row-group

    // ---- band fragments: two L2-hit vector loads (latency hides under staging) ----
    const uint4 bu4 = *(const uint4*)&tab[lane * 8];
    const uint4 au4 = *(const uint4*)&tab[lane * 8 + 4];
    const f16x8 bfrag  = __builtin_bit_cast(f16x8, bu4);
    const f16x8 a2frag = __builtin_bit_cast(f16x8, au4);
    const f32x4 zero4  = {0.f, 0.f, 0.f, 0.f};

    // ---- stage raw P,T (f16) into LDS: 48 rows x 6 groups of 8 px ----
    {
        const float* pimg = pred   + (size_t)img * (IMG * IMG);
        const float* timg = target + (size_t)img * (IMG * IMG);
        if (tx0 > 0 && tx0 < 480 && ty0 > 0 && ty0 < 480) {
            // interior: all halo loads in-bounds, no predication
            #pragma unroll
            for (int i = tid; i < RAWR * 6; i += NT) {
                const int r  = i / 6;
                const int c  = i - r * 6;
                const float* prow = pimg + (ty0 - 5 + r) * IMG + (tx0 - 8 + 8 * c);
                const float* trow = timg + (ty0 - 5 + r) * IMG + (tx0 - 8 + 8 * c);
                const float4 p0 = *(const float4*)(prow);
                const float4 p1 = *(const float4*)(prow + 4);
                const float4 t0 = *(const float4*)(trow);
                const float4 t1 = *(const float4*)(trow + 4);
                const int u = 4 * c;
                *(uint4*)&sRaw[0][r][u] = make_uint4(pk2(p0.x, p0.y), pk2(p0.z, p0.w),
                                                     pk2(p1.x, p1.y), pk2(p1.z, p1.w));
                *(uint4*)&sRaw[1][r][u] = make_uint4(pk2(t0.x, t0.y), pk2(t0.z, t0.w),
                                                     pk2(t1.x, t1.y), pk2(t1.z, t1.w));
            }
        } else {
            for (int i = tid; i < RAWR * 6; i += NT) {
                const int r  = i / 6;
                const int c  = i - r * 6;
                const int gy = ty0 - 5 + r;
                const int gx = tx0 - 8 + 8 * c;
                float4 p0 = make_float4(0.f, 0.f, 0.f, 0.f), p1 = p0, t0 = p0, t1 = p0;
                if ((unsigned)gy < IMG) {
                    const float* prow = pimg + gy * IMG;
                    const float* trow = timg + gy * IMG;
                    if ((unsigned)gx < IMG) {          // gx % 4 == 0
                        p0 = *(const float4*)(prow + gx);
                        t0 = *(const float4*)(trow + gx);
                    }
                    if ((unsigned)(gx + 4) < IMG) {
                        p1 = *(const float4*)(prow + gx + 4);
                        t1 = *(const float4*)(trow + gx + 4);
                    }
                }
                const int u = 4 * c;
                *(uint4*)&sRaw[0][r][u] = make_uint4(pk2(p0.x, p0.y), pk2(p0.z, p0.w),
                                                     pk2(p1.x, p1.y), pk2(p1.z, p1.w));
                *(uint4*)&sRaw[1][r][u] = make_uint4(pk2(t0.x, t0.y), pk2(t0.z, t0.w),
                                                     pk2(t1.x, t1.y), pk2(t1.z, t1.w));
            }
        }
    }
    __syncthreads();

    // ---- prefetch H-conv A-frags to registers (sH will overwrite sRaw) ----
    const int ct0 = wv & 1, mt0 = wv >> 1;
    f16x8 aP0 = __builtin_bit_cast(f16x8, *(const uint4*)&sRaw[0][mt0 * 16 + lm][8 * ct0 + 4 * lg]);
    f16x8 aT0 = __builtin_bit_cast(f16x8, *(const uint4*)&sRaw[1][mt0 * 16 + lm][8 * ct0 + 4 * lg]);
    f16x8 aP1 = aP0, aT1 = aT0;
    if (wv < 2) {
        aP1 = __builtin_bit_cast(f16x8, *(const uint4*)&sRaw[0][32 + lm][8 * wv + 4 * lg]);
        aT1 = __builtin_bit_cast(f16x8, *(const uint4*)&sRaw[1][32 + lm][8 * wv + 4 * lg]);
    }
    __syncthreads();   // all raw reads done; safe to overwrite with sH

    // ---- H-conv: mfma per channel, write h-filtered (f16) column-major ----
    {
        f16x8 af[5];
        af[0] = aP0; af[1] = aT0;
        af[2] = aP0 * aP0;                 // 4x v_pk_mul_f16 each
        af[3] = aT0 * aT0;
        af[4] = aP0 * aT0;
        #pragma unroll
        for (int ch = 0; ch < 5; ++ch) {
            const f32x4 h = __builtin_amdgcn_mfma_f32_16x16x32_f16(af[ch], bfrag, zero4, 0, 0, 0);
            *(uint2*)&sH[ch][16 * ct0 + lm][mt0 * 8 + 2 * lg] =
                make_uint2(pk2(h[0], h[1]), pk2(h[2], h[3]));
        }
    }
    if (wv < 2) {
        f16x8 af[5];
        af[0] = aP1; af[1] = aT1;
        af[2] = aP1 * aP1;
        af[3] = aT1 * aT1;
        af[4] = aP1 * aT1;
        #pragma unroll
        for (int ch = 0; ch < 5; ++ch) {
            const f32x4 h = __builtin_amdgcn_mfma_f32_16x16x32_f16(af[ch], bfrag, zero4, 0, 0, 0);
            *(uint2*)&sH[ch][16 * wv + lm][2 * 8 + 2 * lg] =
                make_uint2(pk2(h[0], h[1]), pk2(h[2], h[3]));
        }
    }
    __syncthreads();

    // ---- V-conv: each wave one 16x16 output quadrant, 5 channels ----
    const int rt  = wv >> 1;
    const int ct2 = wv & 1;
    f32x4 M[5];
    #pragma unroll
    for (int ch = 0; ch < 5; ++ch) {
        const f16x8 b2 = __builtin_bit_cast(f16x8,
            *(const uint4*)&sH[ch][16 * ct2 + lm][8 * rt + 4 * lg]);
        M[ch] = __builtin_amdgcn_mfma_f32_16x16x32_f16(a2frag, b2, zero4, 0, 0, 0);
    }

    // ---- SSIM pointwise + block reduction ----
    float lsum = 0.f;
    #pragma unroll
    for (int r = 0; r < 4; ++r) {
        const float mx = M[0][r], my = M[1][r];
        const float exx = M[2][r], eyy = M[3][r], exy = M[4][r];
        const float mxx = mx * mx, myy = my * my, mxy = mx * my;
        const float sx  = exx - mxx;
        const float sy  = eyy - myy;
        const float sxy = exy - mxy;
        const float num = (2.0f * mxy + 1e-4f) * (2.0f * sxy + 9e-4f);
        const float den = (mxx + myy + 1e-4f) * (sx + sy + 9e-4f);
        lsum = fmaf(num, __builtin_amdgcn_rcpf(den), lsum);
    }
    #pragma unroll
    for (int off = 32; off > 0; off >>= 1)
        lsum += __shfl_down(lsum, off, 64);
    if (lane == 0) sRed[wv] = lsum;
    __syncthreads();
    if (tid == 0)
        partial[bid] = sRed[0] + sRed[1] + sRed[2] + sRed[3];
}

// ---------------------------------------------------------------------------
// Final reduction: sum partials, out = 1 - mean   (1 block x 1024 threads)
// ---------------------------------------------------------------------------
#define NR 1024
__global__ __launch_bounds__(NR) void ssim_reduce_kernel(
    const float* __restrict__ partial, float* __restrict__ out,
    int n, float inv_npix)
{
    __shared__ float sRed[16];
    float s = 0.0f;
    const int n4 = n >> 2;
    for (int i = threadIdx.x; i < n4; i += NR) {
        const float4 v = ((const float4*)partial)[i];
        s += (v.x + v.y) + (v.z + v.w);
    }
    for (int i = (n4 << 2) + threadIdx.x; i < n; i += NR) s += partial[i];
    #pragma unroll
    for (int off = 32; off > 0; off >>= 1)
        s += __shfl_down(s, off, 64);
    if ((threadIdx.x & 63) == 0) sRed[threadIdx.x >> 6] = s;
    __syncthreads();
    if (threadIdx.x == 0) {
        float tot = 0.0f;
        #pragma unroll
        for (int q = 0; q < 16; ++q) tot += sRed[q];
        out[0] = 1.0f - tot * inv_npix;
    }
}

extern "C" void kernel_launch(void* const* d_in, const int* in_sizes, int n_in,
                              void* d_out, int out_size, void* d_ws, size_t ws_size,
                              hipStream_t stream) {
    const float* pred   = (const float*)d_in[0];
    const float* target = (const float*)d_in[1];
    const float* kern   = (const float*)d_in[2];
    float* out     = (float*)d_out;
    unsigned* tab  = (unsigned*)d_ws;                       // 2 KB band table
    float* partial = (float*)d_ws + WS_PARTIAL_OFF;         // per-block sums

    const int nimg    = in_sizes[0] / (IMG * IMG);          // 64
    const int nblocks = (IMG / BT) * (IMG / BT) * nimg;     // 16384 (mult of 8)
    const float inv_npix = 1.0f / ((float)nimg * (float)(IMG * IMG));

    ssim_init_kernel<<<1, 64, 0, stream>>>(kern, tab);
    ssim_mfma_kernel<<<dim3(nblocks), NT, 0, stream>>>(pred, target, tab, partial);
    ssim_reduce_kernel<<<1, NR, 0, stream>>>(partial, out, nblocks, inv_npix);
}